// Round 1
// baseline (188.640 us; speedup 1.0000x reference)
//
#include <hip/hip_runtime.h>
#include <hip/hip_bf16.h>

typedef __attribute__((ext_vector_type(8))) short bf16x8;
typedef __attribute__((ext_vector_type(4))) float f32x4;

__device__ __forceinline__ unsigned short f2bf(float f) {
    unsigned int u = __float_as_uint(f);
    u = (u + 0x7FFFu + ((u >> 16) & 1u)) >> 16;   // round-to-nearest-even
    return (unsigned short)u;
}

// packed fp32x2 -> bf16x2 (v_cvt_pk_bf16_f32 on gfx950); x -> low 16 bits
__device__ __forceinline__ unsigned int pkbf(float x, float y) {
    __hip_bfloat162 h = __float22bfloat162_rn(float2{x, y});
    unsigned int u;
    __builtin_memcpy(&u, &h, 4);
    return u;
}

// ---------------------------------------------------------------------------
// Kernel 1 (fused prep): wct[48][768] bf16 = (w_patch @ [w_reg|w_obj])^T,
// rows 45..47 zero. Replaces btrans + wcomb_partial2 + wcomb_reduce2.
// grid 96 blocks (8 k-columns each), block 512 (8 waves).
//   wave w owns k = blk*8 + w; lane n (n<45 active) accumulates Wc[k][n]
//   over d in two 384-wide chunks staged in LDS.
//   Bw padded to 52 floats/row: lane reads Bw[d][lane] stride-1 -> no bank
//   conflict; Al reads are wave-uniform broadcasts.
// ---------------------------------------------------------------------------
__global__ __launch_bounds__(512) void wcomb_fused(
        const float* __restrict__ wp, const float* __restrict__ wreg,
        const float* __restrict__ wobj, unsigned short* __restrict__ wct) {
    __shared__ float Al[8 * 384];        // [w][dl]  12 KB
    __shared__ float Bw[384 * 52];       // [dl][n]  78 KB (pad 52 = 13x16B)

    const int t    = threadIdx.x;
    const int w    = t >> 6;             // wave id -> k row 0..7
    const int lane = t & 63;             // n (0..44 active, 45..47 zero pad)
    const int kg   = blockIdx.x * 8 + w; // global k column 0..767

    float acc = 0.f;

    #pragma unroll
    for (int ch = 0; ch < 2; ++ch) {
        const int d0 = ch * 384;
        if (ch) __syncthreads();         // protect LDS before restaging

        // --- stage Al[8][384] from wp rows (coalesced f32x4) ---
        for (int e = t; e < 768; e += 512) {
            int r = e / 96, j = e - r * 96;
            *(f32x4*)&Al[r * 384 + j * 4] =
                *(const f32x4*)&wp[(size_t)(blockIdx.x * 8 + r) * 768 + d0 + j * 4];
        }
        // --- stage Bw[384][0..35] from wreg rows (9 f32x4 per 144B row) ---
        for (int e = t; e < 3456; e += 512) {
            int r = e / 9, j = e - r * 9;
            *(f32x4*)&Bw[r * 52 + j * 4] =
                *(const f32x4*)&wreg[(size_t)(d0 + r) * 36 + j * 4];
        }
        // --- stage Bw[384][36..44] from wobj rows (scalar) ---
        for (int e = t; e < 3456; e += 512) {
            int r = e / 9, c = e - r * 9;
            Bw[r * 52 + 36 + c] = wobj[(size_t)(d0 + r) * 9 + c];
        }
        __syncthreads();

        // --- accumulate: acc += sum_dl Al[w][dl] * Bw[dl][lane] ---
        if (lane < 45) {
            const float* alr = &Al[w * 384];
            #pragma unroll 8
            for (int j = 0; j < 96; ++j) {
                f32x4 a = *(const f32x4*)&alr[j * 4];
                acc += a.x * Bw[(j * 4 + 0) * 52 + lane]
                     + a.y * Bw[(j * 4 + 1) * 52 + lane]
                     + a.z * Bw[(j * 4 + 2) * 52 + lane]
                     + a.w * Bw[(j * 4 + 3) * 52 + lane];
            }
        }
    }

    if (lane < 45)      wct[(size_t)lane * 768 + kg] = f2bf(acc);
    else if (lane < 48) wct[(size_t)lane * 768 + kg] = 0;   // zero pad rows
}

// ---------------------------------------------------------------------------
// Kernel 2: main fused GEMM + anchor decode — 4-way K-split, deep prefetch.
// grid 2048 (1 tile = 16 cells x N48 per block), block 256 (4 waves).
// (Proven in prior session — kept byte-identical.)
// ---------------------------------------------------------------------------
__global__ __launch_bounds__(256) void detector_main(
        const float* __restrict__ img, const unsigned short* __restrict__ wct,
        const float* __restrict__ breg, const float* __restrict__ bobj,
        float* __restrict__ out) {
    __shared__ float Co[4][16][49];        // per-wave partial C slabs

    const int t    = threadIdx.x;
    const int lane = t & 63;
    const int wid  = t >> 6;
    const int cl   = lane & 15;
    const int q    = lane >> 4;
    const int tg   = blockIdx.x;           // tile id 0..2047
    const int fj0  = (tg & 1) * 16;
    const int fi   = (tg >> 1) & 31;
    const int b    = tg >> 6;
    const int k0   = wid * 6;              // this wave's first 32-k chunk

    const float* abase = img + (size_t)b * 786432
        + (size_t)(fi * 16 + (q >> 1)) * 512 + (fj0 + cl) * 16 + (q & 1) * 8;
    const unsigned short* bbase = wct + cl * 768 + q * 8;

    #define AOFF(kk) ((size_t)((kk) >> 3) * 262144 + (size_t)((kk) & 7) * 1024)

    f32x4 acc0 = {0.f,0.f,0.f,0.f}, acc1 = acc0, acc2 = acc0;

    // prologue: A(k0), A(k0+1), B(k0)
    f32x4 a0lo = *(const f32x4*)(abase + AOFF(k0));
    f32x4 a0hi = *(const f32x4*)(abase + AOFF(k0) + 4);
    f32x4 a1lo = *(const f32x4*)(abase + AOFF(k0 + 1));
    f32x4 a1hi = *(const f32x4*)(abase + AOFF(k0 + 1) + 4);
    bf16x8 b0x = *(const bf16x8*)(bbase + (size_t)k0 * 32);
    bf16x8 b0y = *(const bf16x8*)(bbase + (size_t)k0 * 32 + 12288);
    bf16x8 b0z = *(const bf16x8*)(bbase + (size_t)k0 * 32 + 24576);

    #pragma unroll
    for (int i = 0; i < 6; ++i) {
        f32x4 a2lo, a2hi;
        if (i < 4) {                                   // compile-time guard
            a2lo = *(const f32x4*)(abase + AOFF(k0 + i + 2));
            a2hi = *(const f32x4*)(abase + AOFF(k0 + i + 2) + 4);
        } else { a2lo = a1lo; a2hi = a1hi; }
        bf16x8 b1x, b1y, b1z;
        if (i < 5) {
            b1x = *(const bf16x8*)(bbase + (size_t)(k0 + i + 1) * 32);
            b1y = *(const bf16x8*)(bbase + (size_t)(k0 + i + 1) * 32 + 12288);
            b1z = *(const bf16x8*)(bbase + (size_t)(k0 + i + 1) * 32 + 24576);
        } else { b1x = b0x; b1y = b0y; b1z = b0z; }

        union { bf16x8 v; unsigned int u[4]; } af;
        af.u[0] = pkbf(a0lo.x, a0lo.y);
        af.u[1] = pkbf(a0lo.z, a0lo.w);
        af.u[2] = pkbf(a0hi.x, a0hi.y);
        af.u[3] = pkbf(a0hi.z, a0hi.w);
        acc0 = __builtin_amdgcn_mfma_f32_16x16x32_bf16(af.v, b0x, acc0, 0, 0, 0);
        acc1 = __builtin_amdgcn_mfma_f32_16x16x32_bf16(af.v, b0y, acc1, 0, 0, 0);
        acc2 = __builtin_amdgcn_mfma_f32_16x16x32_bf16(af.v, b0z, acc2, 0, 0, 0);

        a0lo = a1lo; a0hi = a1hi; a1lo = a2lo; a1hi = a2hi;
        b0x = b1x; b0y = b1y; b0z = b1z;
    }
    #undef AOFF

    // ---- partial C -> per-wave LDS slab (col=cl, row=q*4+r) ----
    #pragma unroll
    for (int r = 0; r < 4; ++r) {
        Co[wid][q * 4 + r][ 0 + cl] = acc0[r];
        Co[wid][q * 4 + r][16 + cl] = acc1[r];
        Co[wid][q * 4 + r][32 + cl] = acc2[r];
    }
    __syncthreads();

    // ---- decode: 16 cells x 9 anchors = 144 rows ----
    for (int rr = t; rr < 144; rr += 256) {
        int cell = rr / 9, k = rr - cell * 9;
        int dfj  = fj0 + cell;
        float v0 = Co[0][cell][4*k+0] + Co[1][cell][4*k+0]
                 + Co[2][cell][4*k+0] + Co[3][cell][4*k+0] + breg[4*k+0];
        float v1 = Co[0][cell][4*k+1] + Co[1][cell][4*k+1]
                 + Co[2][cell][4*k+1] + Co[3][cell][4*k+1] + breg[4*k+1];
        float v2 = Co[0][cell][4*k+2] + Co[1][cell][4*k+2]
                 + Co[2][cell][4*k+2] + Co[3][cell][4*k+2] + breg[4*k+2];
        float v3 = Co[0][cell][4*k+3] + Co[1][cell][4*k+3]
                 + Co[2][cell][4*k+3] + Co[3][cell][4*k+3] + breg[4*k+3];
        float lg = Co[0][cell][36+k]  + Co[1][cell][36+k]
                 + Co[2][cell][36+k]  + Co[3][cell][36+k]  + bobj[k];
        float obj = 1.f / (1.f + __expf(-lg));
        float wc = (float)(dfj * 16) + v0;
        float hc = (float)(fi * 16) + v1;
        float wa = wc + (float)(2 << (k % 3)) * v2;   // BOX_W = 2,4,8 cycling
        float ha = hc + (float)(2 << (k / 3)) * v3;   // BOX_H = 2,2,2,4,4,4,8,8,8
        float* o = out + (size_t)(((b * 32 + fi) * 32 + dfj) * 9 + k) * 7;
        o[0] = wc; o[1] = hc; o[2] = wa; o[3] = ha;
        o[4] = (float)b; o[5] = obj; o[6] = (float)k;
    }
}

extern "C" void kernel_launch(void* const* d_in, const int* in_sizes, int n_in,
                              void* d_out, int out_size, void* d_ws, size_t ws_size,
                              hipStream_t stream) {
    const float* img  = (const float*)d_in[0];
    const float* wp   = (const float*)d_in[1];
    const float* wreg = (const float*)d_in[2];
    const float* breg = (const float*)d_in[3];
    const float* wobj = (const float*)d_in[4];
    const float* bobj = (const float*)d_in[5];
    float* out = (float*)d_out;

    unsigned short* wct = (unsigned short*)d_ws;     // 73728 B (only ws use now)

    wcomb_fused<<<96, 512, 0, stream>>>(wp, wreg, wobj, wct);
    detector_main<<<2048, 256, 0, stream>>>(img, wct, breg, bobj, out);
}

// Round 2
// 170.964 us; speedup vs baseline: 1.1034x; 1.1034x over previous
//
#include <hip/hip_runtime.h>
#include <hip/hip_bf16.h>

typedef __attribute__((ext_vector_type(8))) short bf16x8;
typedef __attribute__((ext_vector_type(4))) float f32x4;

__device__ __forceinline__ unsigned short f2bf(float f) {
    unsigned int u = __float_as_uint(f);
    u = (u + 0x7FFFu + ((u >> 16) & 1u)) >> 16;   // round-to-nearest-even
    return (unsigned short)u;
}

// packed fp32x2 -> bf16x2 (v_cvt_pk_bf16_f32 on gfx950); x -> low 16 bits
__device__ __forceinline__ unsigned int pkbf(float x, float y) {
    __hip_bfloat162 h = __float22bfloat162_rn(float2{x, y});
    unsigned int u;
    __builtin_memcpy(&u, &h, 4);
    return u;
}

// ---------------------------------------------------------------------------
// Kernel 1: Btu[48][768] bf16 = [w_reg | w_obj]^T, rows 45..47 zeroed.
// grid 144, block 256. Same proven indexing as fp32 btrans, bf16 output.
// ---------------------------------------------------------------------------
__global__ __launch_bounds__(256) void btrans_bf16(
        const float* __restrict__ wreg, const float* __restrict__ wobj,
        unsigned short* __restrict__ Btu) {
    const int idx = blockIdx.x * 256 + threadIdx.x;   // n*768 + d
    const int n = idx / 768, d = idx - n * 768;
    float v = 0.f;
    if (n < 36)      v = wreg[(size_t)d * 36 + n];
    else if (n < 45) v = wobj[(size_t)d * 9 + (n - 36)];
    Btu[idx] = f2bf(v);
}

// ---------------------------------------------------------------------------
// Kernel 2: wct[48][768] bf16 = (wp @ [wreg|wobj])^T via MFMA.
// grid 48 (16 k-rows each), block 256 (4 waves, 4-way d-split, 192 each).
// Fragment pattern byte-identical to detector_main's proven one:
//   A lane(cl,q) = wp[kb+cl][d0 + q*8 + j]   (fp32 -> bf16 in-reg)
//   B lane(cl,q) = Btu[cl][d0 + q*8 + j], n-tiles at +0/+12288/+24576
//   C row (m=k) = q*4+r, col (n) = cl; cross-wave reduce via Co[4][16][49].
// ---------------------------------------------------------------------------
__global__ __launch_bounds__(256) void wcomb_mfma(
        const float* __restrict__ wp, const unsigned short* __restrict__ Btu,
        unsigned short* __restrict__ wct) {
    __shared__ float Co[4][16][49];

    const int t    = threadIdx.x;
    const int lane = t & 63;
    const int wid  = t >> 6;
    const int cl   = lane & 15;
    const int q    = lane >> 4;
    const int kb   = blockIdx.x * 16;

    const float* abase = wp + (size_t)(kb + cl) * 768 + q * 8;
    const unsigned short* bbase = Btu + (size_t)cl * 768 + q * 8;
    const int dw = wid * 192;                     // this wave's d-range

    f32x4 acc0 = {0.f,0.f,0.f,0.f}, acc1 = acc0, acc2 = acc0;

    #pragma unroll
    for (int s = 0; s < 6; ++s) {
        const int d0 = dw + s * 32;
        f32x4 alo = *(const f32x4*)(abase + d0);
        f32x4 ahi = *(const f32x4*)(abase + d0 + 4);
        bf16x8 bx = *(const bf16x8*)(bbase + d0);
        bf16x8 by = *(const bf16x8*)(bbase + d0 + 12288);
        bf16x8 bz = *(const bf16x8*)(bbase + d0 + 24576);

        union { bf16x8 v; unsigned int u[4]; } af;
        af.u[0] = pkbf(alo.x, alo.y);
        af.u[1] = pkbf(alo.z, alo.w);
        af.u[2] = pkbf(ahi.x, ahi.y);
        af.u[3] = pkbf(ahi.z, ahi.w);
        acc0 = __builtin_amdgcn_mfma_f32_16x16x32_bf16(af.v, bx, acc0, 0, 0, 0);
        acc1 = __builtin_amdgcn_mfma_f32_16x16x32_bf16(af.v, by, acc1, 0, 0, 0);
        acc2 = __builtin_amdgcn_mfma_f32_16x16x32_bf16(af.v, bz, acc2, 0, 0, 0);
    }

    #pragma unroll
    for (int r = 0; r < 4; ++r) {
        Co[wid][q * 4 + r][ 0 + cl] = acc0[r];
        Co[wid][q * 4 + r][16 + cl] = acc1[r];
        Co[wid][q * 4 + r][32 + cl] = acc2[r];
    }
    __syncthreads();

    // reduce 4 partials, write transposed: wct[n][kb+m]  (768 bf16 per block)
    for (int e = t; e < 768; e += 256) {
        int m = e / 48, n = e - m * 48;
        float s = Co[0][m][n] + Co[1][m][n] + Co[2][m][n] + Co[3][m][n];
        wct[(size_t)n * 768 + kb + m] = f2bf(s);
    }
}

// ---------------------------------------------------------------------------
// Kernel 3: main fused GEMM + anchor decode — 4-way K-split, deep prefetch.
// grid 2048 (1 tile = 16 cells x N48 per block), block 256 (4 waves).
// (Proven — kept byte-identical.)
// ---------------------------------------------------------------------------
__global__ __launch_bounds__(256) void detector_main(
        const float* __restrict__ img, const unsigned short* __restrict__ wct,
        const float* __restrict__ breg, const float* __restrict__ bobj,
        float* __restrict__ out) {
    __shared__ float Co[4][16][49];        // per-wave partial C slabs

    const int t    = threadIdx.x;
    const int lane = t & 63;
    const int wid  = t >> 6;
    const int cl   = lane & 15;
    const int q    = lane >> 4;
    const int tg   = blockIdx.x;           // tile id 0..2047
    const int fj0  = (tg & 1) * 16;
    const int fi   = (tg >> 1) & 31;
    const int b    = tg >> 6;
    const int k0   = wid * 6;              // this wave's first 32-k chunk

    const float* abase = img + (size_t)b * 786432
        + (size_t)(fi * 16 + (q >> 1)) * 512 + (fj0 + cl) * 16 + (q & 1) * 8;
    const unsigned short* bbase = wct + cl * 768 + q * 8;

    #define AOFF(kk) ((size_t)((kk) >> 3) * 262144 + (size_t)((kk) & 7) * 1024)

    f32x4 acc0 = {0.f,0.f,0.f,0.f}, acc1 = acc0, acc2 = acc0;

    // prologue: A(k0), A(k0+1), B(k0)
    f32x4 a0lo = *(const f32x4*)(abase + AOFF(k0));
    f32x4 a0hi = *(const f32x4*)(abase + AOFF(k0) + 4);
    f32x4 a1lo = *(const f32x4*)(abase + AOFF(k0 + 1));
    f32x4 a1hi = *(const f32x4*)(abase + AOFF(k0 + 1) + 4);
    bf16x8 b0x = *(const bf16x8*)(bbase + (size_t)k0 * 32);
    bf16x8 b0y = *(const bf16x8*)(bbase + (size_t)k0 * 32 + 12288);
    bf16x8 b0z = *(const bf16x8*)(bbase + (size_t)k0 * 32 + 24576);

    #pragma unroll
    for (int i = 0; i < 6; ++i) {
        f32x4 a2lo, a2hi;
        if (i < 4) {                                   // compile-time guard
            a2lo = *(const f32x4*)(abase + AOFF(k0 + i + 2));
            a2hi = *(const f32x4*)(abase + AOFF(k0 + i + 2) + 4);
        } else { a2lo = a1lo; a2hi = a1hi; }
        bf16x8 b1x, b1y, b1z;
        if (i < 5) {
            b1x = *(const bf16x8*)(bbase + (size_t)(k0 + i + 1) * 32);
            b1y = *(const bf16x8*)(bbase + (size_t)(k0 + i + 1) * 32 + 12288);
            b1z = *(const bf16x8*)(bbase + (size_t)(k0 + i + 1) * 32 + 24576);
        } else { b1x = b0x; b1y = b0y; b1z = b0z; }

        union { bf16x8 v; unsigned int u[4]; } af;
        af.u[0] = pkbf(a0lo.x, a0lo.y);
        af.u[1] = pkbf(a0lo.z, a0lo.w);
        af.u[2] = pkbf(a0hi.x, a0hi.y);
        af.u[3] = pkbf(a0hi.z, a0hi.w);
        acc0 = __builtin_amdgcn_mfma_f32_16x16x32_bf16(af.v, b0x, acc0, 0, 0, 0);
        acc1 = __builtin_amdgcn_mfma_f32_16x16x32_bf16(af.v, b0y, acc1, 0, 0, 0);
        acc2 = __builtin_amdgcn_mfma_f32_16x16x32_bf16(af.v, b0z, acc2, 0, 0, 0);

        a0lo = a1lo; a0hi = a1hi; a1lo = a2lo; a1hi = a2hi;
        b0x = b1x; b0y = b1y; b0z = b1z;
    }
    #undef AOFF

    // ---- partial C -> per-wave LDS slab (col=cl, row=q*4+r) ----
    #pragma unroll
    for (int r = 0; r < 4; ++r) {
        Co[wid][q * 4 + r][ 0 + cl] = acc0[r];
        Co[wid][q * 4 + r][16 + cl] = acc1[r];
        Co[wid][q * 4 + r][32 + cl] = acc2[r];
    }
    __syncthreads();

    // ---- decode: 16 cells x 9 anchors = 144 rows ----
    for (int rr = t; rr < 144; rr += 256) {
        int cell = rr / 9, k = rr - cell * 9;
        int dfj  = fj0 + cell;
        float v0 = Co[0][cell][4*k+0] + Co[1][cell][4*k+0]
                 + Co[2][cell][4*k+0] + Co[3][cell][4*k+0] + breg[4*k+0];
        float v1 = Co[0][cell][4*k+1] + Co[1][cell][4*k+1]
                 + Co[2][cell][4*k+1] + Co[3][cell][4*k+1] + breg[4*k+1];
        float v2 = Co[0][cell][4*k+2] + Co[1][cell][4*k+2]
                 + Co[2][cell][4*k+2] + Co[3][cell][4*k+2] + breg[4*k+2];
        float v3 = Co[0][cell][4*k+3] + Co[1][cell][4*k+3]
                 + Co[2][cell][4*k+3] + Co[3][cell][4*k+3] + breg[4*k+3];
        float lg = Co[0][cell][36+k]  + Co[1][cell][36+k]
                 + Co[2][cell][36+k]  + Co[3][cell][36+k]  + bobj[k];
        float obj = 1.f / (1.f + __expf(-lg));
        float wc = (float)(dfj * 16) + v0;
        float hc = (float)(fi * 16) + v1;
        float wa = wc + (float)(2 << (k % 3)) * v2;   // BOX_W = 2,4,8 cycling
        float ha = hc + (float)(2 << (k / 3)) * v3;   // BOX_H = 2,2,2,4,4,4,8,8,8
        float* o = out + (size_t)(((b * 32 + fi) * 32 + dfj) * 9 + k) * 7;
        o[0] = wc; o[1] = hc; o[2] = wa; o[3] = ha;
        o[4] = (float)b; o[5] = obj; o[6] = (float)k;
    }
}

extern "C" void kernel_launch(void* const* d_in, const int* in_sizes, int n_in,
                              void* d_out, int out_size, void* d_ws, size_t ws_size,
                              hipStream_t stream) {
    const float* img  = (const float*)d_in[0];
    const float* wp   = (const float*)d_in[1];
    const float* wreg = (const float*)d_in[2];
    const float* breg = (const float*)d_in[3];
    const float* wobj = (const float*)d_in[4];
    const float* bobj = (const float*)d_in[5];
    float* out = (float*)d_out;

    unsigned short* wct = (unsigned short*)d_ws;               // 73728 B
    unsigned short* Btu = (unsigned short*)((char*)d_ws + 73728); // 73728 B

    btrans_bf16<<<144, 256, 0, stream>>>(wreg, wobj, Btu);
    wcomb_mfma<<<48, 256, 0, stream>>>(wp, Btu, wct);
    detector_main<<<2048, 256, 0, stream>>>(img, wct, breg, bobj, out);
}